// Round 1
// baseline (4084.452 us; speedup 1.0000x reference)
//
#include <hip/hip_runtime.h>
#include <math.h>

#define NTOK 4096
#define DMODEL 512
#define NHEAD 8
#define DHEAD 64
#define CTXN 77
#define CTXD 768

// ---------------------------------------------------------------- LayerNorm
__global__ __launch_bounds__(256) void ln512_kernel(const float* __restrict__ in,
    float* __restrict__ out, const float* __restrict__ g, const float* __restrict__ bta) {
  int row = blockIdx.x;
  const float* p = in + (size_t)row * DMODEL;
  int t = threadIdx.x;
  float a0 = p[t], a1 = p[t + 256];
  float s = a0 + a1;
#pragma unroll
  for (int o = 32; o; o >>= 1) s += __shfl_xor(s, o, 64);
  __shared__ float red[4];
  int w = t >> 6, lane = t & 63;
  if (lane == 0) red[w] = s;
  __syncthreads();
  s = red[0] + red[1] + red[2] + red[3];
  float mean = s * (1.0f / DMODEL);
  float d0 = a0 - mean, d1 = a1 - mean;
  float v = d0 * d0 + d1 * d1;
#pragma unroll
  for (int o = 32; o; o >>= 1) v += __shfl_xor(v, o, 64);
  __syncthreads();
  if (lane == 0) red[w] = v;
  __syncthreads();
  v = (red[0] + red[1] + red[2] + red[3]) * (1.0f / DMODEL);
  float rs = rsqrtf(v + 1e-5f);
  float* q = out + (size_t)row * DMODEL;
  q[t]       = d0 * rs * g[t]       + bta[t];
  q[t + 256] = d1 * rs * g[t + 256] + bta[t + 256];
}

// ---------------------------------------------------------------- generic GEMM
// C[M,Nc] = A[M,K] @ W[K,Nc] (+bias) (+resid). Nc = gridDim.x*64 (mult of 64),
// K mult of 16. M guarded.
__global__ __launch_bounds__(256) void gemm_kernel(
    const float* __restrict__ A, int lda,
    const float* __restrict__ W, int ldw,
    float* __restrict__ C, int ldc,
    const float* __restrict__ bias,
    const float* __restrict__ resid, int ldr,
    int M, int K) {
  __shared__ __align__(16) float As[16][68];
  __shared__ __align__(16) float Ws[16][64];
  int tid = threadIdx.x;
  int tx = tid & 15, ty = tid >> 4;
  int m0 = blockIdx.y * 64, n0 = blockIdx.x * 64;
  int ak = tid & 15, am = tid >> 4;
  int wn = tid & 63, wk = tid >> 6;
  float acc[4][4] = {};
  for (int k0 = 0; k0 < K; k0 += 16) {
#pragma unroll
    for (int p = 0; p < 4; p++) {
      int m = am + p * 16;
      int gm = m0 + m;
      As[ak][m] = (gm < M) ? A[(size_t)gm * lda + k0 + ak] : 0.0f;
    }
#pragma unroll
    for (int p = 0; p < 4; p++) {
      int k = wk + p * 4;
      Ws[k][wn] = W[(size_t)(k0 + k) * ldw + n0 + wn];
    }
    __syncthreads();
#pragma unroll
    for (int kk = 0; kk < 16; kk++) {
      float a_[4], b_[4];
      *(float4*)a_ = *(const float4*)&As[kk][ty * 4];
      *(float4*)b_ = *(const float4*)&Ws[kk][tx * 4];
#pragma unroll
      for (int i = 0; i < 4; i++)
#pragma unroll
        for (int j = 0; j < 4; j++)
          acc[i][j] = fmaf(a_[i], b_[j], acc[i][j]);
    }
    __syncthreads();
  }
  int gn0 = n0 + tx * 4;
#pragma unroll
  for (int i = 0; i < 4; i++) {
    int gm = m0 + ty * 4 + i;
    if (gm >= M) continue;
    float o_[4];
#pragma unroll
    for (int j = 0; j < 4; j++) o_[j] = acc[i][j];
    if (bias) {
#pragma unroll
      for (int j = 0; j < 4; j++) o_[j] += bias[gn0 + j];
    }
    if (resid) {
      float r_[4];
      *(float4*)r_ = *(const float4*)&resid[(size_t)gm * ldr + gn0];
#pragma unroll
      for (int j = 0; j < 4; j++) o_[j] += r_[j];
    }
    *(float4*)&C[(size_t)gm * ldc + gn0] = *(float4*)o_;
  }
}

// ---------------------------------------------------------------- self QK^T
// sim[bh, i, j] = scale * dot64(q[b,i,h*64:], k[b,j,h*64:])
__global__ __launch_bounds__(256) void self_scores_kernel(
    const float* __restrict__ q, const float* __restrict__ k, float* __restrict__ sim) {
  __shared__ __align__(16) float Qs[64][68];
  __shared__ __align__(16) float Ks[64][68];
  int bh = blockIdx.z;
  int b = bh >> 3, h = bh & 7;
  int i0 = blockIdx.y * 64, j0 = blockIdx.x * 64;
  int tid = threadIdx.x;
  int kd = tid & 63, r4 = tid >> 6;
  const float* qb = q + (size_t)b * NTOK * DMODEL + h * DHEAD;
  const float* kb = k + (size_t)b * NTOK * DMODEL + h * DHEAD;
#pragma unroll
  for (int p = 0; p < 16; p++) {
    int i = r4 + p * 4;
    Qs[kd][i] = qb[(size_t)(i0 + i) * DMODEL + kd];
    Ks[kd][i] = kb[(size_t)(j0 + i) * DMODEL + kd];
  }
  __syncthreads();
  int tx = tid & 15, ty = tid >> 4;
  float acc[4][4] = {};
#pragma unroll 8
  for (int kk = 0; kk < 64; kk++) {
    float a_[4], b_[4];
    *(float4*)a_ = *(const float4*)&Qs[kk][ty * 4];
    *(float4*)b_ = *(const float4*)&Ks[kk][tx * 4];
#pragma unroll
    for (int i = 0; i < 4; i++)
#pragma unroll
      for (int j = 0; j < 4; j++)
        acc[i][j] = fmaf(a_[i], b_[j], acc[i][j]);
  }
  float* ob = sim + (size_t)bh * NTOK * NTOK;
#pragma unroll
  for (int i = 0; i < 4; i++) {
    float o_[4];
#pragma unroll
    for (int j = 0; j < 4; j++) o_[j] = acc[i][j] * 0.125f;  // 64^-0.5
    *(float4*)&ob[(size_t)(i0 + ty * 4 + i) * NTOK + j0 + tx * 4] = *(float4*)o_;
  }
}

// ---------------------------------------------------------------- row softmax (4096 cols, in-place)
__global__ __launch_bounds__(256) void softmax4096_kernel(float* __restrict__ P) {
  float* r = P + (size_t)blockIdx.x * NTOK;
  int t = threadIdx.x;
  float v[16];
  float mx = -3.4e38f;
#pragma unroll
  for (int i = 0; i < 16; i++) { v[i] = r[t + i * 256]; mx = fmaxf(mx, v[i]); }
#pragma unroll
  for (int o = 32; o; o >>= 1) mx = fmaxf(mx, __shfl_xor(mx, o, 64));
  __shared__ float red[4];
  int w = t >> 6, lane = t & 63;
  if (lane == 0) red[w] = mx;
  __syncthreads();
  mx = fmaxf(fmaxf(red[0], red[1]), fmaxf(red[2], red[3]));
  float s = 0.0f;
#pragma unroll
  for (int i = 0; i < 16; i++) { v[i] = __expf(v[i] - mx); s += v[i]; }
#pragma unroll
  for (int o = 32; o; o >>= 1) s += __shfl_xor(s, o, 64);
  __syncthreads();
  if (lane == 0) red[w] = s;
  __syncthreads();
  s = red[0] + red[1] + red[2] + red[3];
  float inv = 1.0f / s;
#pragma unroll
  for (int i = 0; i < 16; i++) r[t + i * 256] = v[i] * inv;
}

// ---------------------------------------------------------------- P @ V (self)
__global__ __launch_bounds__(256) void attn_pv_kernel(
    const float* __restrict__ P, const float* __restrict__ V, float* __restrict__ out) {
  __shared__ __align__(16) float Ps[64][68];
  __shared__ __align__(16) float Vs[64][64];
  int bh = blockIdx.z;
  int b = bh >> 3, h = bh & 7;
  int i0 = blockIdx.y * 64;
  const float* Pb = P + (size_t)bh * NTOK * NTOK;
  const float* vb = V + (size_t)b * NTOK * DMODEL + h * DHEAD;
  int tid = threadIdx.x;
  int c = tid & 63, r4 = tid >> 6;
  int tx = tid & 15, ty = tid >> 4;
  float acc[4][4] = {};
  for (int j0 = 0; j0 < NTOK; j0 += 64) {
#pragma unroll
    for (int p = 0; p < 16; p++) {
      int rr = r4 + p * 4;
      Ps[c][rr] = Pb[(size_t)(i0 + rr) * NTOK + j0 + c];
      Vs[rr][c] = vb[(size_t)(j0 + rr) * DMODEL + c];
    }
    __syncthreads();
#pragma unroll 8
    for (int kk = 0; kk < 64; kk++) {
      float a_[4], b_[4];
      *(float4*)a_ = *(const float4*)&Ps[kk][ty * 4];
      *(float4*)b_ = *(const float4*)&Vs[kk][tx * 4];
#pragma unroll
      for (int i = 0; i < 4; i++)
#pragma unroll
        for (int j = 0; j < 4; j++)
          acc[i][j] = fmaf(a_[i], b_[j], acc[i][j]);
    }
    __syncthreads();
  }
  float* ob = out + (size_t)b * NTOK * DMODEL + h * DHEAD;
#pragma unroll
  for (int i = 0; i < 4; i++) {
    float o_[4];
#pragma unroll
    for (int j = 0; j < 4; j++) o_[j] = acc[i][j];
    *(float4*)&ob[(size_t)(i0 + ty * 4 + i) * DMODEL + tx * 4] = *(float4*)o_;
  }
}

// ---------------------------------------------------------------- fused cross-attention
// one wave per query row; writes probs (b*h, i, 77) and out (pre-proj)
__global__ __launch_bounds__(256) void cross_attn_kernel(
    const float* __restrict__ q, const float* __restrict__ k2,
    const float* __restrict__ v2, float* __restrict__ probs, float* __restrict__ out) {
  __shared__ float sp[4][80];
  int tid = threadIdx.x;
  int w = tid >> 6, lane = tid & 63;
  int r = blockIdx.x * 4 + w;          // (b*H + h)*N + i
  int b = r >> 15;
  int h = (r >> 12) & 7;
  int i = r & 4095;
  float qd = q[((size_t)b * NTOK + i) * DMODEL + h * DHEAD + lane];
  const float* kb = k2 + (size_t)b * CTXN * DMODEL + h * DHEAD;
  const float* vb = v2 + (size_t)b * CTXN * DMODEL + h * DHEAD;
  for (int j = 0; j < CTXN; j++) {
    float s = qd * kb[(size_t)j * DMODEL + lane];
#pragma unroll
    for (int o = 32; o; o >>= 1) s += __shfl_xor(s, o, 64);
    if (lane == 0) sp[w][j] = s * 0.125f;
  }
  __syncthreads();
  float s0 = sp[w][lane];
  float s1 = (lane < 13) ? sp[w][64 + lane] : -3.4e38f;
  float m = fmaxf(s0, s1);
#pragma unroll
  for (int o = 32; o; o >>= 1) m = fmaxf(m, __shfl_xor(m, o, 64));
  float e0 = __expf(s0 - m);
  float e1 = (lane < 13) ? __expf(s1 - m) : 0.0f;
  float l = e0 + e1;
#pragma unroll
  for (int o = 32; o; o >>= 1) l += __shfl_xor(l, o, 64);
  float inv = 1.0f / l;
  float p0 = e0 * inv, p1 = e1 * inv;
  size_t rowbase = (size_t)r * CTXN;
  probs[rowbase + lane] = p0;
  if (lane < 13) probs[rowbase + 64 + lane] = p1;
  __syncthreads();
  sp[w][lane] = p0;
  if (lane < 13) sp[w][64 + lane] = p1;
  __syncthreads();
  float acc = 0.0f;
  for (int j = 0; j < CTXN; j++)
    acc = fmaf(sp[w][j], vb[(size_t)j * DMODEL + lane], acc);
  out[((size_t)b * NTOK + i) * DMODEL + h * DHEAD + lane] = acc;
}

// ---------------------------------------------------------------- GEGLU (in-place: h[:, :2048] = hx * gelu(gate))
__global__ __launch_bounds__(256) void geglu_kernel(float* __restrict__ hbuf) {
  size_t idx = (size_t)blockIdx.x * 256 + threadIdx.x;   // 2*4096*2048 total
  size_t row = idx >> 11;
  int c = (int)(idx & 2047);
  float* base = hbuf + row * 4096;
  float hx = base[c];
  float g = base[2048 + c];
  float gl = 0.5f * g * (1.0f + erff(g * 0.70710678118654752f));
  base[c] = hx * gl;
}

// ---------------------------------------------------------------- launcher
extern "C" void kernel_launch(void* const* d_in, const int* in_sizes, int n_in,
                              void* d_out, int out_size, void* d_ws, size_t ws_size,
                              hipStream_t stream) {
  const float* x    = (const float*)d_in[0];
  const float* ctx  = (const float*)d_in[1];
  const float* ln1g = (const float*)d_in[2];
  const float* ln1b = (const float*)d_in[3];
  const float* ln2g = (const float*)d_in[4];
  const float* ln2b = (const float*)d_in[5];
  const float* ln3g = (const float*)d_in[6];
  const float* ln3b = (const float*)d_in[7];
  const float* wq1  = (const float*)d_in[8];
  const float* wk1  = (const float*)d_in[9];
  const float* wv1  = (const float*)d_in[10];
  const float* wo1  = (const float*)d_in[11];
  const float* bo1  = (const float*)d_in[12];
  const float* wq2  = (const float*)d_in[13];
  const float* wk2  = (const float*)d_in[14];
  const float* wv2  = (const float*)d_in[15];
  const float* wo2  = (const float*)d_in[16];
  const float* bo2  = (const float*)d_in[17];
  const float* ffw1 = (const float*)d_in[18];
  const float* ffb1 = (const float*)d_in[19];
  const float* ffw2 = (const float*)d_in[20];
  const float* ffb2 = (const float*)d_in[21];

  float* ws = (float*)d_ws;
  float* XN = ws +  0;          // 2*4096*512
  float* Qb = ws +  4194304;
  float* Kb = ws +  8388608;
  float* Vb = ws + 12582912;
  float* AO = ws + 16777216;
  float* XB = ws + 20971520;
  float* HB = ws + 25165824;    // 2*4096*4096

  float* outx      = (float*)d_out;
  float* self_map  = outx + 4194304;     // 16*4096*4096
  float* cross_map = outx + 272629760;   // 16*4096*77

  const float* NUL = nullptr;

  // ---- self-attention ----
  ln512_kernel<<<dim3(8192), dim3(256), 0, stream>>>(x, XN, ln1g, ln1b);
  gemm_kernel<<<dim3(8,128), dim3(256), 0, stream>>>(XN,512, wq1,512, Qb,512, NUL, NUL,0, 8192,512);
  gemm_kernel<<<dim3(8,128), dim3(256), 0, stream>>>(XN,512, wk1,512, Kb,512, NUL, NUL,0, 8192,512);
  gemm_kernel<<<dim3(8,128), dim3(256), 0, stream>>>(XN,512, wv1,512, Vb,512, NUL, NUL,0, 8192,512);
  self_scores_kernel<<<dim3(64,64,16), dim3(256), 0, stream>>>(Qb, Kb, self_map);
  softmax4096_kernel<<<dim3(65536), dim3(256), 0, stream>>>(self_map);
  attn_pv_kernel<<<dim3(1,64,16), dim3(256), 0, stream>>>(self_map, Vb, AO);
  gemm_kernel<<<dim3(8,128), dim3(256), 0, stream>>>(AO,512, wo1,512, XB,512, bo1, x,512, 8192,512);

  // ---- cross-attention ----
  ln512_kernel<<<dim3(8192), dim3(256), 0, stream>>>(XB, XN, ln2g, ln2b);
  gemm_kernel<<<dim3(8,128), dim3(256), 0, stream>>>(XN,512, wq2,512, Qb,512, NUL, NUL,0, 8192,512);
  gemm_kernel<<<dim3(8,3),   dim3(256), 0, stream>>>(ctx,768, wk2,512, Kb,512, NUL, NUL,0, 154,768);
  gemm_kernel<<<dim3(8,3),   dim3(256), 0, stream>>>(ctx,768, wv2,512, Vb,512, NUL, NUL,0, 154,768);
  cross_attn_kernel<<<dim3(16384), dim3(256), 0, stream>>>(Qb, Kb, Vb, cross_map, AO);
  gemm_kernel<<<dim3(8,128), dim3(256), 0, stream>>>(AO,512, wo2,512, XB,512, bo2, XB,512, 8192,512);

  // ---- GEGLU feed-forward ----
  ln512_kernel<<<dim3(8192), dim3(256), 0, stream>>>(XB, XN, ln3g, ln3b);
  gemm_kernel<<<dim3(64,128), dim3(256), 0, stream>>>(XN,512, ffw1,4096, HB,4096, ffb1, NUL,0, 8192,512);
  geglu_kernel<<<dim3(65536), dim3(256), 0, stream>>>(HB);
  gemm_kernel<<<dim3(8,128), dim3(256), 0, stream>>>(HB,4096, ffw2,512, outx,512, ffb2, XB,512, 8192,2048);
}